// Round 17
// baseline (9835.069 us; speedup 1.0000x reference)
//
#include <hip/hip_runtime.h>

#define T_STEPS 1024
#define BSZ 256
#define HD 256
#define OUTC 64
#define WSTEPS 16
#define NWIN (T_STEPS / WSTEPS)
#define WREG 48   // k-quads of Wi2h h-part in registers (C phase)
#define WTAIL 16  // k-quads of Wi2h h-part in LDS

// ---------------- ws layout (float offsets) ----------------
static const size_t OFF_SUM  = 0;        // [256][256] f32  (Sum_t outs)
static const size_t OFF_FLAG = 65536;    // int flag (x is int64?)
static const size_t OFF_WP   = 65792;    // 3 x [128][256] float4 packed weights

// x-dtype detector: if x is int64, all sampled high 32-bit words are zero.
__global__ void detect_x(const int* __restrict__ x, float* __restrict__ ws) {
    __shared__ int nonzero;
    if (threadIdx.x == 0) nonzero = 0;
    __syncthreads();
    if (x[2 * threadIdx.x + 1] != 0) nonzero = 1;   // benign same-value race
    __syncthreads();
    if (threadIdx.x == 0) *(int*)(ws + OFF_FLAG) = (nonzero == 0) ? 1 : 0;
}

// Pack weights as float4 per (k-quad, column): Wp[z][q][j] = {W_z[j][4q+c]}.
// Values identical to source -> FMA chains stay bit-identical.
__global__ void prep_pack(const float* __restrict__ Wi2h,
                          const float* __restrict__ Wi2o,
                          const float* __restrict__ Wo2o,
                          float* __restrict__ ws) {
    const int q = blockIdx.x;            // 0..127 (k quad)
    const int z = blockIdx.y;            // 0..2
    const int j = threadIdx.x;           // 0..255 (column)
    const float* src = (z == 0) ? Wi2h : (z == 1) ? Wi2o : Wo2o;
    const float4 v = *reinterpret_cast<const float4*>(src + (size_t)j * 512 + 4 * q);
    reinterpret_cast<float4*>(ws + OFF_WP)[((size_t)z * 128 + q) * 256 + j] = v;
}

// exact-bit wave broadcast: value of v at lane l
__device__ __forceinline__ float RLf(float v, int l) {
    return __int_as_float(__builtin_amdgcn_readlane(__float_as_int(v), l));
}

// Bit-faithful f32 scan, two-wave-group version.
// amdgpu_waves_per_eu(2,2): a 512-thread block needs exactly 2 waves/SIMD
// resident (LDS caps at 1 block/CU) -> VGPR budget 512/2 = 256, so the
// C-phase register weights (whr[48] = 192 VGPR) fit WITHOUT scratch spills
// (R15/R16 were silently capped at 128 -> whr spilled onto C's serial path).
// 256 blocks x 512 threads; 1 batch row per block. Thread (grp, j) owns
// column j; group g handles window-steps t = 8g..8g+7 in the t-parallel
// phases (B, D2, D). C (the truly sequential 16 steps) runs on group 0 only
// while group 1 parks at the barriers. The t-ascending f32 fold of Sum_t is
// preserved exactly: group 1 ships raw a2 via LDS, group 0 folds t=0..15 in
// order with the identical (a2 + boo_j) adds. All per-element fmaf chains
// are the identical k-ascending sequences of the validated R7 kernel.
__attribute__((amdgpu_waves_per_eu(2, 2)))
__global__ void __launch_bounds__(512) scan_all(
    const int* __restrict__ x, const float* __restrict__ emb,
    const float* __restrict__ bih, const float* __restrict__ bio,
    const float* __restrict__ boo, float* __restrict__ ws) {
    const int tid = threadIdx.x;
    const int j = tid & 255;            // column
    const int lane = tid & 63;
    const int grp = tid >> 8;           // wave group 0/1
    const int tbase = grp * 8;          // group's first t in window
    const int row = blockIdx.x;
    const int mode64 = *(const int*)(ws + OFF_FLAG);

    const float4* __restrict__ Wh4  = reinterpret_cast<const float4*>(ws + OFF_WP);
    const float4* __restrict__ Wio4 = Wh4 + (size_t)128 * 256;
    const float4* __restrict__ Woo4 = Wh4 + (size_t)256 * 256;

    __shared__ __align__(16) float eW[WSTEPS][256];        // 16 KB
    __shared__ __align__(16) float hHist[WSTEPS + 1][256]; // 17 KB
    __shared__ __align__(16) float oHist[WSTEPS][256];     // 16 KB
    __shared__ float aHb[WSTEPS][256];                     // 16 KB (also a2 hop)
    __shared__ float aOb[WSTEPS][256];                     // 16 KB
    __shared__ float wTail[WTAIL][4][256];                 // 64 KB
    __shared__ int toks[WSTEPS];
    // total ~145 KB -> 1 block/CU, 8 waves = 2/SIMD

    // stage Wi2h h-part tail quads (k-quads 64+WREG..127); group g stages 8
    #pragma unroll
    for (int k = 0; k < 8; ++k) {
        const int qq = tbase + k;
        const float4 v = Wh4[(size_t)(64 + WREG + qq) * 256 + j];
        wTail[qq][0][j] = v.x; wTail[qq][1][j] = v.y;
        wTail[qq][2][j] = v.z; wTail[qq][3][j] = v.w;
    }

    const float bih_j = bih[j], bio_j = bio[j], boo_j = boo[j];
    float sum = 0.f;                    // meaningful for grp 0 only
    if (tid < 256) hHist[WSTEPS][j] = 0.f;   // h_0 = 0 seed (slot 16)
    __syncthreads();

    #pragma unroll 1
    for (int w = 0; w < NWIN; ++w) {
        // ---- A: tokens; carry h (slot16 -> slot0); stage e rows
        if (tid < WSTEPS) {
            const int idx = (w * WSTEPS + tid) * BSZ + row;
            toks[tid] = mode64 ? x[2 * idx] : x[idx];
        }
        if (tid < 256) hHist[0][j] = hHist[WSTEPS][j];
        __syncthreads();
        #pragma unroll
        for (int u = 0; u < 8; ++u)
            eW[tbase + u][j] = emb[(size_t)toks[tbase + u] * HD + j];
        __syncthreads();

        // ---- B: e-part chains (k = 0..255) for this group's 8 t's
        float aH[8], aO[8];
        #pragma unroll
        for (int u = 0; u < 8; ++u) { aH[u] = 0.f; aO[u] = 0.f; }
        #pragma unroll 2
        for (int q = 0; q < 64; ++q) {
            const float4 wh = Wh4[(size_t)q * 256 + j];
            const float4 wo = Wio4[(size_t)q * 256 + j];
            #pragma unroll
            for (int u = 0; u < 8; ++u) {
                const float4 e = *reinterpret_cast<const float4*>(&eW[tbase + u][4 * q]);
                float h = aH[u], o = aO[u];
                h = fmaf(e.x, wh.x, h); o = fmaf(e.x, wo.x, o);
                h = fmaf(e.y, wh.y, h); o = fmaf(e.y, wo.y, o);
                h = fmaf(e.z, wh.z, h); o = fmaf(e.z, wo.z, o);
                h = fmaf(e.w, wh.w, h); o = fmaf(e.w, wo.w, o);
                aH[u] = h; aO[u] = o;
            }
        }
        #pragma unroll
        for (int u = 0; u < 8; ++u) {
            aHb[tbase + u][j] = aH[u];   // own slot: exact f32 hop
            aOb[tbase + u][j] = aO[u];
        }

        // ---- C: 16 sequential steps (group 0 only; group 1 parks)
        {
            float4 whr[WREG];
            if (grp == 0) {
                #pragma unroll
                for (int qq = 0; qq < WREG; ++qq)
                    whr[qq] = Wh4[(size_t)(64 + qq) * 256 + j];
            }
            #pragma unroll 1
            for (int t = 0; t < WSTEPS; ++t) {
                __syncthreads();          // hHist[t] + (t=0: aHb both groups)
                if (grp == 0) {
                    const float4 h4 = *reinterpret_cast<const float4*>(&hHist[t][4 * lane]);
                    float ah = aHb[t][j];
                    #pragma unroll
                    for (int qq = 0; qq < WREG; ++qq) {
                        ah = fmaf(RLf(h4.x, qq), whr[qq].x, ah);
                        ah = fmaf(RLf(h4.y, qq), whr[qq].y, ah);
                        ah = fmaf(RLf(h4.z, qq), whr[qq].z, ah);
                        ah = fmaf(RLf(h4.w, qq), whr[qq].w, ah);
                    }
                    #pragma unroll
                    for (int qq = 0; qq < WTAIL; ++qq) {
                        const int l = WREG + qq;
                        ah = fmaf(RLf(h4.x, l), wTail[qq][0][j], ah);
                        ah = fmaf(RLf(h4.y, l), wTail[qq][1][j], ah);
                        ah = fmaf(RLf(h4.z, l), wTail[qq][2][j], ah);
                        ah = fmaf(RLf(h4.w, l), wTail[qq][3][j], ah);
                    }
                    hHist[t + 1][j] = ah + bih_j;   // + b_i2h
                }
            }
            __syncthreads();              // all h states published
        }

        // ---- D2: o's h-part (k = 256..511) for group's 8 t's
        {
            float4 hv[8]; float aOr[8];
            #pragma unroll
            for (int u = 0; u < 8; ++u) {
                hv[u] = *reinterpret_cast<const float4*>(&hHist[tbase + u][4 * lane]);
                aOr[u] = aOb[tbase + u][j];
            }
            #pragma unroll 2
            for (int q = 0; q < 64; ++q) {
                const float4 w4 = Wio4[(size_t)(64 + q) * 256 + j];
                #pragma unroll
                for (int u = 0; u < 8; ++u) {
                    float s;
                    s = RLf(hv[u].x, q); aOr[u] = fmaf(s, w4.x, aOr[u]);
                    s = RLf(hv[u].y, q); aOr[u] = fmaf(s, w4.y, aOr[u]);
                    s = RLf(hv[u].z, q); aOr[u] = fmaf(s, w4.z, aOr[u]);
                    s = RLf(hv[u].w, q); aOr[u] = fmaf(s, w4.w, aOr[u]);
                }
            }
            #pragma unroll
            for (int u = 0; u < 8; ++u)
                oHist[tbase + u][j] = aOr[u] + bio_j;    // + b_i2o
        }
        __syncthreads();                 // o published

        // ---- D: out-chains for group's 8 t's (hn part, then o part)
        float a2[8];
        #pragma unroll
        for (int u = 0; u < 8; ++u) a2[u] = 0.f;
        {
            float4 hv[8];
            #pragma unroll
            for (int u = 0; u < 8; ++u)
                hv[u] = *reinterpret_cast<const float4*>(&hHist[tbase + u + 1][4 * lane]);
            #pragma unroll 2
            for (int q = 0; q < 64; ++q) {
                const float4 w4 = Woo4[(size_t)q * 256 + j];
                #pragma unroll
                for (int u = 0; u < 8; ++u) {
                    float s;
                    s = RLf(hv[u].x, q); a2[u] = fmaf(s, w4.x, a2[u]);
                    s = RLf(hv[u].y, q); a2[u] = fmaf(s, w4.y, a2[u]);
                    s = RLf(hv[u].z, q); a2[u] = fmaf(s, w4.z, a2[u]);
                    s = RLf(hv[u].w, q); a2[u] = fmaf(s, w4.w, a2[u]);
                }
            }
            float4 ov[8];
            #pragma unroll
            for (int u = 0; u < 8; ++u)
                ov[u] = *reinterpret_cast<const float4*>(&oHist[tbase + u][4 * lane]);
            #pragma unroll 2
            for (int q = 0; q < 64; ++q) {
                const float4 w4 = Woo4[(size_t)(64 + q) * 256 + j];
                #pragma unroll
                for (int u = 0; u < 8; ++u) {
                    float s;
                    s = RLf(ov[u].x, q); a2[u] = fmaf(s, w4.x, a2[u]);
                    s = RLf(ov[u].y, q); a2[u] = fmaf(s, w4.y, a2[u]);
                    s = RLf(ov[u].z, q); a2[u] = fmaf(s, w4.z, a2[u]);
                    s = RLf(ov[u].w, q); a2[u] = fmaf(s, w4.w, a2[u]);
                }
            }
        }

        // ---- fold: strict t-ascending order across both groups
        if (grp == 1) {
            #pragma unroll
            for (int u = 0; u < 8; ++u) aHb[u][j] = a2[u];   // raw a2, t=8+u
        }
        __syncthreads();
        if (grp == 0) {
            #pragma unroll
            for (int u = 0; u < 8; ++u) sum += (a2[u] + boo_j);       // t=0..7
            #pragma unroll
            for (int u = 0; u < 8; ++u) sum += (aHb[u][j] + boo_j);   // t=8..15
        }
        // next A's writes (toks, hHist[0]) are grp0-only and happen after its
        // fold; eW staging is gated by A's barrier; aHb rewritten in next B
        // only after the eW barrier. No cross-window races.
    }

    if (tid < 256) ws[OFF_SUM + (size_t)row * 256 + j] = sum;
}

// encoded = Sum/1024 (exact); logits = seq-k FMA + b_pred; log_softmax with
// f64-CR exp/log; first-index argmax over f32 lp.
__global__ __launch_bounds__(64) void final_k(
    const float* __restrict__ Wpred, const float* __restrict__ bpred,
    const float* __restrict__ ws, float* __restrict__ out) {
    const int b = blockIdx.x, o = threadIdx.x;
    __shared__ float enc[256];
    __shared__ float exs[64];
    __shared__ float s32s;

    #pragma unroll
    for (int u = 0; u < 4; ++u)
        enc[o * 4 + u] = ws[OFF_SUM + (size_t)b * 256 + o * 4 + u] * (1.0f / 1024.0f);
    __syncthreads();

    float acc = 0.f;
    for (int e = 0; e < 256; ++e)
        acc = fmaf(enc[e], Wpred[(size_t)o * 256 + e], acc);
    acc += bpred[o];                      // logits[b][o], f32

    float m = acc;
    #pragma unroll
    for (int d = 1; d < 64; d <<= 1) m = fmaxf(m, __shfl_xor(m, d));
    const float sh = acc - m;
    const float ex = (float)exp((double)sh);
    exs[o] = ex;
    __syncthreads();
    if (o == 0) {
        double sd = 0.0;
        for (int i = 0; i < 64; ++i) sd += (double)exs[i];
        s32s = (float)sd;
    }
    __syncthreads();
    const float log_s = (float)log((double)s32s);
    const float lp = sh - log_s;
    const float pr = (float)exp((double)lp);

    float av = lp; int ai = o;
    #pragma unroll
    for (int d = 1; d < 64; d <<= 1) {
        const float ov = __shfl_xor(av, d);
        const int oi = __shfl_xor(ai, d);
        if (ov > av || (ov == av && oi < ai)) { av = ov; ai = oi; }
    }

    out[BSZ + (size_t)b * OUTC + o] = lp;              // logprobs
    out[BSZ + 16384 + (size_t)b * OUTC + o] = pr;      // probs
    if (o == 0) out[b] = (float)ai;                    // preds
}

// ---------------- host ----------------
extern "C" void kernel_launch(void* const* d_in, const int* in_sizes, int n_in,
                              void* d_out, int out_size, void* d_ws, size_t ws_size,
                              hipStream_t stream) {
    const int*   x     = (const int*)d_in[0];
    const float* emb   = (const float*)d_in[1];
    const float* Wi2h  = (const float*)d_in[2];
    const float* b_ih  = (const float*)d_in[3];
    const float* Wi2o  = (const float*)d_in[4];
    const float* b_io  = (const float*)d_in[5];
    const float* Wo2o  = (const float*)d_in[6];
    const float* b_oo  = (const float*)d_in[7];
    const float* Wpred = (const float*)d_in[8];
    const float* b_p   = (const float*)d_in[9];
    float* ws  = (float*)d_ws;
    float* out = (float*)d_out;

    detect_x<<<1, 256, 0, stream>>>(x, ws);
    prep_pack<<<dim3(128, 3), 256, 0, stream>>>(Wi2h, Wi2o, Wo2o, ws);
    scan_all<<<dim3(256), 512, 0, stream>>>(x, emb, b_ih, b_io, b_oo, ws);
    final_k<<<dim3(256), 64, 0, stream>>>(Wpred, b_p, ws, out);
}

// Round 18
// 7871.095 us; speedup vs baseline: 1.2495x; 1.2495x over previous
//
#include <hip/hip_runtime.h>

#define T_STEPS 1024
#define BSZ 256
#define HD 256
#define OUTC 64
#define NT 32           // steps per phase
#define NPHASE 32
#define TT 16           // steps per kernB/kernD block
#define NTILE (NT / TT) // 2

// ---------------- ws layout (float offsets), total ~35.7 MB ----------------
static const size_t OFF_SUM  = 0;                      // [256][256]
static const size_t OFF_FLAG = 65536;                  // int flag
static const size_t OFF_WP   = 65600;                  // 3 x [128][256] float4
static const size_t OFF_CEH  = 458816;                 // [NT][256][256]
static const size_t OFF_CEO  = 2555968;                // [NT][256][256]
static const size_t OFF_H    = 4653120;                // [NT+1][256][256]
static const size_t OFF_A2   = 6815808;                // [NT][256][256]
// end: 8,912,960 floats

// x-dtype detector: if x is int64, all sampled high 32-bit words are zero.
__global__ void detect_x(const int* __restrict__ x, float* __restrict__ ws) {
    __shared__ int nonzero;
    if (threadIdx.x == 0) nonzero = 0;
    __syncthreads();
    if (x[2 * threadIdx.x + 1] != 0) nonzero = 1;   // benign same-value race
    __syncthreads();
    if (threadIdx.x == 0) *(int*)(ws + OFF_FLAG) = (nonzero == 0) ? 1 : 0;
}

// Pack weights as float4 per (k-quad, column): Wp[z][q][j] = {W_z[j][4q+c]}.
__global__ void prep_pack(const float* __restrict__ Wi2h,
                          const float* __restrict__ Wi2o,
                          const float* __restrict__ Wo2o,
                          float* __restrict__ ws) {
    const int q = blockIdx.x;            // 0..127 (k quad)
    const int z = blockIdx.y;            // 0..2
    const int j = threadIdx.x;           // 0..255 (column)
    const float* src = (z == 0) ? Wi2h : (z == 1) ? Wi2o : Wo2o;
    const float4 v = *reinterpret_cast<const float4*>(src + (size_t)j * 512 + 4 * q);
    reinterpret_cast<float4*>(ws + OFF_WP)[((size_t)z * 128 + q) * 256 + j] = v;
}

// exact-bit wave broadcast: value of v at lane l
__device__ __forceinline__ float RLf(float v, int l) {
    return __int_as_float(__builtin_amdgcn_readlane(__float_as_int(v), l));
}

// ---- kernB: e-part chains (k=0..255) for hn and o, TT steps per block.
// Bit-exact prefix of the validated R7 chains; partials stored as f32 (exact).
__global__ __launch_bounds__(256) void kernB(
    const int* __restrict__ x, const float* __restrict__ emb,
    float* __restrict__ ws, int phase) {
    const int j = threadIdx.x;
    const int ti = blockIdx.x;          // t-tile within phase
    const int row = blockIdx.y;
    const int mode64 = *(const int*)(ws + OFF_FLAG);
    const float4* __restrict__ Wh4  = reinterpret_cast<const float4*>(ws + OFF_WP);
    const float4* __restrict__ Wio4 = Wh4 + (size_t)128 * 256;

    __shared__ __align__(16) float eW[TT][256];
    __shared__ int toks[TT];
    if (j < TT) {
        const int t = phase * NT + ti * TT + j;
        const int idx = t * BSZ + row;
        toks[j] = mode64 ? x[2 * idx] : x[idx];
    }
    __syncthreads();
    #pragma unroll
    for (int u = 0; u < TT; ++u) eW[u][j] = emb[(size_t)toks[u] * HD + j];
    __syncthreads();

    float aH[TT], aO[TT];
    #pragma unroll
    for (int u = 0; u < TT; ++u) { aH[u] = 0.f; aO[u] = 0.f; }
    #pragma unroll 2
    for (int q = 0; q < 64; ++q) {
        const float4 wh = Wh4[(size_t)q * 256 + j];
        const float4 wo = Wio4[(size_t)q * 256 + j];
        #pragma unroll
        for (int u = 0; u < TT; ++u) {
            const float4 e = *reinterpret_cast<const float4*>(&eW[u][4 * q]);
            float h = aH[u], o = aO[u];
            h = fmaf(e.x, wh.x, h); o = fmaf(e.x, wo.x, o);
            h = fmaf(e.y, wh.y, h); o = fmaf(e.y, wo.y, o);
            h = fmaf(e.z, wh.z, h); o = fmaf(e.z, wo.z, o);
            h = fmaf(e.w, wh.w, h); o = fmaf(e.w, wo.w, o);
            aH[u] = h; aO[u] = o;
        }
    }
    const size_t rb = (size_t)row * 256 + j;
    #pragma unroll
    for (int u = 0; u < TT; ++u) {
        const size_t off = (size_t)(ti * TT + u) * 65536 + rb;
        ws[OFF_CEH + off] = aH[u];
        ws[OFF_CEO + off] = aO[u];
    }
}

// ---- kernC: NT sequential recurrence steps. Wi2h h-part fully register-
// resident (whr[64] = 256 VGPR; 256-thread blocks provably get this budget,
// R12). h broadcast via readlane from one distributed b128. Continues the
// exact chains from ce_h (f32 hop), writes h states to ws for kernD.
__global__ __launch_bounds__(256) void kernC(
    const float* __restrict__ bih, float* __restrict__ ws, int phase) {
    const int j = threadIdx.x;
    const int lane = j & 63;
    const int row = blockIdx.x;
    const float4* __restrict__ Wh4 = reinterpret_cast<const float4*>(ws + OFF_WP);

    float4 whr[64];
    #pragma unroll
    for (int q = 0; q < 64; ++q) whr[q] = Wh4[(size_t)(64 + q) * 256 + j];

    __shared__ __align__(16) float hCur[256];
    float* __restrict__ Hp = ws + OFF_H;
    const float* __restrict__ CE = ws + OFF_CEH;
    const size_t rb = (size_t)row * 256 + j;

    const float hc = (phase == 0) ? 0.f : Hp[(size_t)NT * 65536 + rb]; // carry
    Hp[rb] = hc;                       // H[0] = h at phase start (for kernD)
    hCur[j] = hc;
    const float bih_j = bih[j];
    float ceCur = CE[rb];
    __syncthreads();

    #pragma unroll 1
    for (int i = 0; i < NT; ++i) {
        const float ceNext = (i + 1 < NT) ? CE[(size_t)(i + 1) * 65536 + rb] : 0.f;
        const float4 h4 = *reinterpret_cast<const float4*>(&hCur[4 * lane]);
        float ah = ceCur;
        #pragma unroll
        for (int q = 0; q < 64; ++q) {
            ah = fmaf(RLf(h4.x, q), whr[q].x, ah);
            ah = fmaf(RLf(h4.y, q), whr[q].y, ah);
            ah = fmaf(RLf(h4.z, q), whr[q].z, ah);
            ah = fmaf(RLf(h4.w, q), whr[q].w, ah);
        }
        const float hn = ah + bih_j;                   // + b_i2h
        Hp[(size_t)(i + 1) * 65536 + rb] = hn;         // publish to ws
        __syncthreads();                               // all h4 reads done
        hCur[j] = hn;
        ceCur = ceNext;
        __syncthreads();                               // hCur published
    }
}

// ---- kernD: finish o (h-part, k=256..511) and the out-chains for TT steps.
// h states staged in LDS; broadcasts are same-address b128 reads (exact).
__global__ __launch_bounds__(256) void kernD(
    const float* __restrict__ bio, float* __restrict__ ws, int phase) {
    const int j = threadIdx.x;
    const int ti = blockIdx.x;
    const int row = blockIdx.y;
    const float4* __restrict__ Wh4  = reinterpret_cast<const float4*>(ws + OFF_WP);
    const float4* __restrict__ Wio4 = Wh4 + (size_t)128 * 256;
    const float4* __restrict__ Woo4 = Wh4 + (size_t)256 * 256;

    __shared__ __align__(16) float hS[TT + 1][256];
    __shared__ __align__(16) float oS[TT][256];
    const float* __restrict__ Hp = ws + OFF_H;
    const size_t rb = (size_t)row * 256 + j;

    #pragma unroll
    for (int u = 0; u <= TT; ++u)
        hS[u][j] = Hp[(size_t)(ti * TT + u) * 65536 + rb];
    float co[TT];
    #pragma unroll
    for (int u = 0; u < TT; ++u)
        co[u] = ws[OFF_CEO + (size_t)(ti * TT + u) * 65536 + rb];
    __syncthreads();

    // o's h-part: k = 256..511 over h_t (= hS[u]), continuing ce_o chains
    #pragma unroll 2
    for (int q = 0; q < 64; ++q) {
        const float4 w4 = Wio4[(size_t)(64 + q) * 256 + j];
        #pragma unroll
        for (int u = 0; u < TT; ++u) {
            const float4 h = *reinterpret_cast<const float4*>(&hS[u][4 * q]);
            float o = co[u];
            o = fmaf(h.x, w4.x, o); o = fmaf(h.y, w4.y, o);
            o = fmaf(h.z, w4.z, o); o = fmaf(h.w, w4.w, o);
            co[u] = o;
        }
    }
    const float bio_j = bio[j];
    #pragma unroll
    for (int u = 0; u < TT; ++u) oS[u][j] = co[u] + bio_j;   // + b_i2o
    __syncthreads();

    // out-chains: hn part (k=0..255, hn = hS[u+1]) then o part (k=256..511)
    float a2[TT];
    #pragma unroll
    for (int u = 0; u < TT; ++u) a2[u] = 0.f;
    #pragma unroll 2
    for (int q = 0; q < 64; ++q) {
        const float4 w4 = Woo4[(size_t)q * 256 + j];
        #pragma unroll
        for (int u = 0; u < TT; ++u) {
            const float4 v = *reinterpret_cast<const float4*>(&hS[u + 1][4 * q]);
            float a = a2[u];
            a = fmaf(v.x, w4.x, a); a = fmaf(v.y, w4.y, a);
            a = fmaf(v.z, w4.z, a); a = fmaf(v.w, w4.w, a);
            a2[u] = a;
        }
    }
    #pragma unroll 2
    for (int q = 0; q < 64; ++q) {
        const float4 w4 = Woo4[(size_t)(64 + q) * 256 + j];
        #pragma unroll
        for (int u = 0; u < TT; ++u) {
            const float4 v = *reinterpret_cast<const float4*>(&oS[u][4 * q]);
            float a = a2[u];
            a = fmaf(v.x, w4.x, a); a = fmaf(v.y, w4.y, a);
            a = fmaf(v.z, w4.z, a); a = fmaf(v.w, w4.w, a);
            a2[u] = a;
        }
    }
    #pragma unroll
    for (int u = 0; u < TT; ++u)
        ws[OFF_A2 + (size_t)(ti * TT + u) * 65536 + rb] = a2[u];
}

// ---- kernF: fold a2 into SUM, strictly t-ascending (exact f32 order):
// sum += (a2[t] + boo_j), phases processed in launch order.
__global__ __launch_bounds__(256) void kernF(
    const float* __restrict__ boo, float* __restrict__ ws, int phase) {
    const int j = threadIdx.x;
    const int b = blockIdx.x;
    const size_t rb = (size_t)b * 256 + j;
    float s = (phase == 0) ? 0.f : ws[OFF_SUM + rb];
    const float boo_j = boo[j];
    const float* __restrict__ A2 = ws + OFF_A2;
    #pragma unroll 4
    for (int i = 0; i < NT; ++i) s += (A2[(size_t)i * 65536 + rb] + boo_j);
    ws[OFF_SUM + rb] = s;
}

// encoded = Sum/1024 (exact); logits = seq-k FMA + b_pred; log_softmax with
// f64-CR exp/log; first-index argmax over f32 lp.
__global__ __launch_bounds__(64) void final_k(
    const float* __restrict__ Wpred, const float* __restrict__ bpred,
    const float* __restrict__ ws, float* __restrict__ out) {
    const int b = blockIdx.x, o = threadIdx.x;
    __shared__ float enc[256];
    __shared__ float exs[64];
    __shared__ float s32s;

    #pragma unroll
    for (int u = 0; u < 4; ++u)
        enc[o * 4 + u] = ws[OFF_SUM + (size_t)b * 256 + o * 4 + u] * (1.0f / 1024.0f);
    __syncthreads();

    float acc = 0.f;
    for (int e = 0; e < 256; ++e)
        acc = fmaf(enc[e], Wpred[(size_t)o * 256 + e], acc);
    acc += bpred[o];                      // logits[b][o], f32

    float m = acc;
    #pragma unroll
    for (int d = 1; d < 64; d <<= 1) m = fmaxf(m, __shfl_xor(m, d));
    const float sh = acc - m;
    const float ex = (float)exp((double)sh);
    exs[o] = ex;
    __syncthreads();
    if (o == 0) {
        double sd = 0.0;
        for (int i = 0; i < 64; ++i) sd += (double)exs[i];
        s32s = (float)sd;
    }
    __syncthreads();
    const float log_s = (float)log((double)s32s);
    const float lp = sh - log_s;
    const float pr = (float)exp((double)lp);

    float av = lp; int ai = o;
    #pragma unroll
    for (int d = 1; d < 64; d <<= 1) {
        const float ov = __shfl_xor(av, d);
        const int oi = __shfl_xor(ai, d);
        if (ov > av || (ov == av && oi < ai)) { av = ov; ai = oi; }
    }

    out[BSZ + (size_t)b * OUTC + o] = lp;              // logprobs
    out[BSZ + 16384 + (size_t)b * OUTC + o] = pr;      // probs
    if (o == 0) out[b] = (float)ai;                    // preds
}

// ---------------- host ----------------
extern "C" void kernel_launch(void* const* d_in, const int* in_sizes, int n_in,
                              void* d_out, int out_size, void* d_ws, size_t ws_size,
                              hipStream_t stream) {
    const int*   x     = (const int*)d_in[0];
    const float* emb   = (const float*)d_in[1];
    const float* Wi2h  = (const float*)d_in[2];
    const float* b_ih  = (const float*)d_in[3];
    const float* Wi2o  = (const float*)d_in[4];
    const float* b_io  = (const float*)d_in[5];
    const float* Wo2o  = (const float*)d_in[6];
    const float* b_oo  = (const float*)d_in[7];
    const float* Wpred = (const float*)d_in[8];
    const float* b_p   = (const float*)d_in[9];
    float* ws  = (float*)d_ws;
    float* out = (float*)d_out;

    detect_x<<<1, 256, 0, stream>>>(x, ws);
    prep_pack<<<dim3(128, 3), 256, 0, stream>>>(Wi2h, Wi2o, Wo2o, ws);

    for (int p = 0; p < NPHASE; ++p) {
        kernB<<<dim3(NTILE, 256), 256, 0, stream>>>(x, emb, ws, p);
        kernC<<<dim3(256), 256, 0, stream>>>(b_ih, ws, p);
        kernD<<<dim3(NTILE, 256), 256, 0, stream>>>(b_io, ws, p);
        kernF<<<dim3(256), 256, 0, stream>>>(b_oo, ws, p);
    }
    final_k<<<dim3(256), 64, 0, stream>>>(Wpred, b_p, ws, out);
}

// Round 19
// 7063.517 us; speedup vs baseline: 1.3924x; 1.1143x over previous
//
#include <hip/hip_runtime.h>

#define T_STEPS 1024
#define BSZ 256
#define HD 256
#define OUTC 64
#define NT 32           // steps per phase
#define NPHASE 32
#define TB 8            // steps per kernB/kernD block
#define NTILE (NT / TB) // 4

// ---------------- ws layout (float offsets), total ~35.7 MB ----------------
static const size_t OFF_SUM  = 0;                      // [256][256]
static const size_t OFF_FLAG = 65536;                  // int flag
static const size_t OFF_WP   = 65600;                  // 3 x [128][256] float4
static const size_t OFF_CEH  = 458816;                 // [NT][256][256]
static const size_t OFF_CEO  = 2555968;                // [NT][256][256]
static const size_t OFF_H    = 4653120;                // [NT+1][256][256]
static const size_t OFF_A2   = 6815808;                // [NT][256][256]

// x-dtype detector: if x is int64, all sampled high 32-bit words are zero.
__global__ void detect_x(const int* __restrict__ x, float* __restrict__ ws) {
    __shared__ int nonzero;
    if (threadIdx.x == 0) nonzero = 0;
    __syncthreads();
    if (x[2 * threadIdx.x + 1] != 0) nonzero = 1;   // benign same-value race
    __syncthreads();
    if (threadIdx.x == 0) *(int*)(ws + OFF_FLAG) = (nonzero == 0) ? 1 : 0;
}

// Pack weights as float4 per (k-quad, column): Wp[z][q][j] = {W_z[j][4q+c]}.
__global__ void prep_pack(const float* __restrict__ Wi2h,
                          const float* __restrict__ Wi2o,
                          const float* __restrict__ Wo2o,
                          float* __restrict__ ws) {
    const int q = blockIdx.x;            // 0..127 (k quad)
    const int z = blockIdx.y;            // 0..2
    const int j = threadIdx.x;           // 0..255 (column)
    const float* src = (z == 0) ? Wi2h : (z == 1) ? Wi2o : Wo2o;
    const float4 v = *reinterpret_cast<const float4*>(src + (size_t)j * 512 + 4 * q);
    reinterpret_cast<float4*>(ws + OFF_WP)[((size_t)z * 128 + q) * 256 + j] = v;
}

// exact-bit wave broadcast: value of v at lane l
__device__ __forceinline__ float RLf(float v, int l) {
    return __int_as_float(__builtin_amdgcn_readlane(__float_as_int(v), l));
}

// ---- kernB: e-part chains (k=0..255) for hn and o, TB steps per block.
// e distributed in wave registers (coalesced global b128), broadcast via
// readlane -> no DS-pipe serialization. ti==0 blocks also fold the PREVIOUS
// phase's a2 into SUM (strict t-ascending f32 order, exact).
__global__ __launch_bounds__(256) void kernB(
    const int* __restrict__ x, const float* __restrict__ emb,
    const float* __restrict__ boo, float* __restrict__ ws, int phase) {
    const int j = threadIdx.x;
    const int lane = j & 63;
    const int ti = blockIdx.x;          // 0..NTILE-1
    const int row = blockIdx.y;
    const int mode64 = *(const int*)(ws + OFF_FLAG);
    const float4* __restrict__ Wh4  = reinterpret_cast<const float4*>(ws + OFF_WP);
    const float4* __restrict__ Wio4 = Wh4 + (size_t)128 * 256;

    // fold previous phase's a2 into SUM (t-ascending, exact f32 chain)
    if (ti == 0 && phase > 0) {
        const size_t rb = (size_t)row * 256 + j;
        float av[NT];
        #pragma unroll
        for (int i = 0; i < NT; ++i)
            av[i] = ws[OFF_A2 + (size_t)i * 65536 + rb];
        float s = (phase == 1) ? 0.f : ws[OFF_SUM + rb];
        const float boo_j = boo[j];
        #pragma unroll
        for (int i = 0; i < NT; ++i) s += (av[i] + boo_j);
        ws[OFF_SUM + rb] = s;
    }

    __shared__ int toks[TB];
    if (j < TB) {
        const int t = phase * NT + ti * TB + j;
        const int idx = t * BSZ + row;
        toks[j] = mode64 ? x[2 * idx] : x[idx];
    }
    __syncthreads();
    float4 e4[TB];
    #pragma unroll
    for (int u = 0; u < TB; ++u)
        e4[u] = *reinterpret_cast<const float4*>(emb + (size_t)toks[u] * HD + 4 * lane);

    float aH[TB], aO[TB];
    #pragma unroll
    for (int u = 0; u < TB; ++u) { aH[u] = 0.f; aO[u] = 0.f; }
    #pragma unroll 2
    for (int q = 0; q < 64; ++q) {
        const float4 wh = Wh4[(size_t)q * 256 + j];
        const float4 wo = Wio4[(size_t)q * 256 + j];
        #pragma unroll
        for (int u = 0; u < TB; ++u) {
            float s;
            s = RLf(e4[u].x, q); aH[u] = fmaf(s, wh.x, aH[u]); aO[u] = fmaf(s, wo.x, aO[u]);
            s = RLf(e4[u].y, q); aH[u] = fmaf(s, wh.y, aH[u]); aO[u] = fmaf(s, wo.y, aO[u]);
            s = RLf(e4[u].z, q); aH[u] = fmaf(s, wh.z, aH[u]); aO[u] = fmaf(s, wo.z, aO[u]);
            s = RLf(e4[u].w, q); aH[u] = fmaf(s, wh.w, aH[u]); aO[u] = fmaf(s, wo.w, aO[u]);
        }
    }
    const size_t rb = (size_t)row * 256 + j;
    #pragma unroll
    for (int u = 0; u < TB; ++u) {
        const size_t off = (size_t)(ti * TB + u) * 65536 + rb;
        ws[OFF_CEH + off] = aH[u];
        ws[OFF_CEO + off] = aO[u];
    }
}

// ---- kernC: NT sequential recurrence steps; whr[64] register-resident,
// h broadcast via readlane (unchanged from R18 — already efficient).
__global__ __launch_bounds__(256) void kernC(
    const float* __restrict__ bih, float* __restrict__ ws, int phase) {
    const int j = threadIdx.x;
    const int lane = j & 63;
    const int row = blockIdx.x;
    const float4* __restrict__ Wh4 = reinterpret_cast<const float4*>(ws + OFF_WP);

    float4 whr[64];
    #pragma unroll
    for (int q = 0; q < 64; ++q) whr[q] = Wh4[(size_t)(64 + q) * 256 + j];

    __shared__ __align__(16) float hCur[256];
    float* __restrict__ Hp = ws + OFF_H;
    const float* __restrict__ CE = ws + OFF_CEH;
    const size_t rb = (size_t)row * 256 + j;

    const float hc = (phase == 0) ? 0.f : Hp[(size_t)NT * 65536 + rb]; // carry
    Hp[rb] = hc;                       // H[0] = h at phase start
    hCur[j] = hc;
    const float bih_j = bih[j];
    float ceCur = CE[rb];
    __syncthreads();

    #pragma unroll 1
    for (int i = 0; i < NT; ++i) {
        const float ceNext = (i + 1 < NT) ? CE[(size_t)(i + 1) * 65536 + rb] : 0.f;
        const float4 h4 = *reinterpret_cast<const float4*>(&hCur[4 * lane]);
        float ah = ceCur;
        #pragma unroll
        for (int q = 0; q < 64; ++q) {
            ah = fmaf(RLf(h4.x, q), whr[q].x, ah);
            ah = fmaf(RLf(h4.y, q), whr[q].y, ah);
            ah = fmaf(RLf(h4.z, q), whr[q].z, ah);
            ah = fmaf(RLf(h4.w, q), whr[q].w, ah);
        }
        const float hn = ah + bih_j;                   // + b_i2h
        Hp[(size_t)(i + 1) * 65536 + rb] = hn;         // publish to ws
        __syncthreads();                               // all h4 reads done
        hCur[j] = hn;
        ceCur = ceNext;
        __syncthreads();                               // hCur published
    }
}

// ---- kernD: finish o (h-part) and out-chains for TB steps, readlane
// broadcasts from register-distributed h/o vectors. Chains 1 (o h-part,
// uses h_t = hv[u]) and 2 (out hn-part, uses h_{t+1} = hv[u+1]) fused in
// one q-loop sharing readlanes; chain 3 (out o-part) after the oS hop.
__global__ __launch_bounds__(256) void kernD(
    const float* __restrict__ bio, float* __restrict__ ws, int phase) {
    const int j = threadIdx.x;
    const int lane = j & 63;
    const int ti = blockIdx.x;
    const int row = blockIdx.y;
    const float4* __restrict__ Wh4  = reinterpret_cast<const float4*>(ws + OFF_WP);
    const float4* __restrict__ Wio4 = Wh4 + (size_t)128 * 256;
    const float4* __restrict__ Woo4 = Wh4 + (size_t)256 * 256;

    __shared__ __align__(16) float oS[TB][256];
    const float* __restrict__ Hp = ws + OFF_H;
    const size_t rb = (size_t)row * 256;

    float4 hv[TB + 1];
    #pragma unroll
    for (int u = 0; u <= TB; ++u)
        hv[u] = *reinterpret_cast<const float4*>(
            Hp + (size_t)(ti * TB + u) * 65536 + rb + 4 * lane);
    float co[TB], a2[TB];
    #pragma unroll
    for (int u = 0; u < TB; ++u) {
        co[u] = ws[OFF_CEO + (size_t)(ti * TB + u) * 65536 + rb + j];
        a2[u] = 0.f;
    }

    // fused chains 1+2
    #pragma unroll 2
    for (int q = 0; q < 64; ++q) {
        const float4 w1 = Wio4[(size_t)(64 + q) * 256 + j];
        const float4 w2 = Woo4[(size_t)q * 256 + j];
        float sx[TB + 1], sy[TB + 1], sz[TB + 1], sw[TB + 1];
        #pragma unroll
        for (int u = 0; u <= TB; ++u) {
            sx[u] = RLf(hv[u].x, q); sy[u] = RLf(hv[u].y, q);
            sz[u] = RLf(hv[u].z, q); sw[u] = RLf(hv[u].w, q);
        }
        #pragma unroll
        for (int u = 0; u < TB; ++u) {
            co[u] = fmaf(sx[u], w1.x, co[u]);
            co[u] = fmaf(sy[u], w1.y, co[u]);
            co[u] = fmaf(sz[u], w1.z, co[u]);
            co[u] = fmaf(sw[u], w1.w, co[u]);
            a2[u] = fmaf(sx[u + 1], w2.x, a2[u]);
            a2[u] = fmaf(sy[u + 1], w2.y, a2[u]);
            a2[u] = fmaf(sz[u + 1], w2.z, a2[u]);
            a2[u] = fmaf(sw[u + 1], w2.w, a2[u]);
        }
    }
    const float bio_j = bio[j];
    #pragma unroll
    for (int u = 0; u < TB; ++u) oS[u][j] = co[u] + bio_j;   // + b_i2o
    __syncthreads();
    float4 ov[TB];
    #pragma unroll
    for (int u = 0; u < TB; ++u)
        ov[u] = *reinterpret_cast<const float4*>(&oS[u][4 * lane]);

    // chain 3: out o-part (k = 256..511)
    #pragma unroll 2
    for (int q = 0; q < 64; ++q) {
        const float4 w3 = Woo4[(size_t)(64 + q) * 256 + j];
        #pragma unroll
        for (int u = 0; u < TB; ++u) {
            a2[u] = fmaf(RLf(ov[u].x, q), w3.x, a2[u]);
            a2[u] = fmaf(RLf(ov[u].y, q), w3.y, a2[u]);
            a2[u] = fmaf(RLf(ov[u].z, q), w3.z, a2[u]);
            a2[u] = fmaf(RLf(ov[u].w, q), w3.w, a2[u]);
        }
    }
    #pragma unroll
    for (int u = 0; u < TB; ++u)
        ws[OFF_A2 + (size_t)(ti * TB + u) * 65536 + rb + j] = a2[u];
}

// encoded: fold LAST phase's a2 (t-ascending, exact), /1024; logits; softmax;
// first-index argmax over f32 lp.
__global__ __launch_bounds__(64) void final_k(
    const float* __restrict__ Wpred, const float* __restrict__ bpred,
    const float* __restrict__ boo, const float* __restrict__ ws,
    float* __restrict__ out) {
    const int b = blockIdx.x, o = threadIdx.x;
    __shared__ float enc[256];
    __shared__ float exs[64];
    __shared__ float s32s;

    #pragma unroll
    for (int u = 0; u < 4; ++u) {
        const int j = o * 4 + u;
        const size_t rb = (size_t)b * 256 + j;
        float av[NT];
        #pragma unroll
        for (int i = 0; i < NT; ++i)
            av[i] = ws[OFF_A2 + (size_t)i * 65536 + rb];
        float s = ws[OFF_SUM + rb];
        const float boo_j = boo[j];
        #pragma unroll
        for (int i = 0; i < NT; ++i) s += (av[i] + boo_j);
        enc[j] = s * (1.0f / 1024.0f);
    }
    __syncthreads();

    float acc = 0.f;
    for (int e = 0; e < 256; ++e)
        acc = fmaf(enc[e], Wpred[(size_t)o * 256 + e], acc);
    acc += bpred[o];                      // logits[b][o], f32

    float m = acc;
    #pragma unroll
    for (int d = 1; d < 64; d <<= 1) m = fmaxf(m, __shfl_xor(m, d));
    const float sh = acc - m;
    const float ex = (float)exp((double)sh);
    exs[o] = ex;
    __syncthreads();
    if (o == 0) {
        double sd = 0.0;
        for (int i = 0; i < 64; ++i) sd += (double)exs[i];
        s32s = (float)sd;
    }
    __syncthreads();
    const float log_s = (float)log((double)s32s);
    const float lp = sh - log_s;
    const float pr = (float)exp((double)lp);

    float av = lp; int ai = o;
    #pragma unroll
    for (int d = 1; d < 64; d <<= 1) {
        const float ov = __shfl_xor(av, d);
        const int oi = __shfl_xor(ai, d);
        if (ov > av || (ov == av && oi < ai)) { av = ov; ai = oi; }
    }

    out[BSZ + (size_t)b * OUTC + o] = lp;              // logprobs
    out[BSZ + 16384 + (size_t)b * OUTC + o] = pr;      // probs
    if (o == 0) out[b] = (float)ai;                    // preds
}

// ---------------- host ----------------
extern "C" void kernel_launch(void* const* d_in, const int* in_sizes, int n_in,
                              void* d_out, int out_size, void* d_ws, size_t ws_size,
                              hipStream_t stream) {
    const int*   x     = (const int*)d_in[0];
    const float* emb   = (const float*)d_in[1];
    const float* Wi2h  = (const float*)d_in[2];
    const float* b_ih  = (const float*)d_in[3];
    const float* Wi2o  = (const float*)d_in[4];
    const float* b_io  = (const float*)d_in[5];
    const float* Wo2o  = (const float*)d_in[6];
    const float* b_oo  = (const float*)d_in[7];
    const float* Wpred = (const float*)d_in[8];
    const float* b_p   = (const float*)d_in[9];
    float* ws  = (float*)d_ws;
    float* out = (float*)d_out;

    detect_x<<<1, 256, 0, stream>>>(x, ws);
    prep_pack<<<dim3(128, 3), 256, 0, stream>>>(Wi2h, Wi2o, Wo2o, ws);

    for (int p = 0; p < NPHASE; ++p) {
        kernB<<<dim3(NTILE, 256), 256, 0, stream>>>(x, emb, b_oo, ws, p);
        kernC<<<dim3(256), 256, 0, stream>>>(b_ih, ws, p);
        kernD<<<dim3(NTILE, 256), 256, 0, stream>>>(b_io, ws, p);
    }
    final_k<<<dim3(256), 64, 0, stream>>>(Wpred, b_p, b_oo, ws, out);
}

// Round 20
// 5599.049 us; speedup vs baseline: 1.7566x; 1.2616x over previous
//
#include <hip/hip_runtime.h>

#define T_STEPS 1024
#define BSZ 256
#define HD 256
#define OUTC 64
#define NT 32           // steps per phase
#define NPHASE 32
#define TBB 8           // steps per subgroup in kernB/kernD
#define BT 16           // steps per kernB/kernD block (2 subgroups)

// ---------------- ws layout (float offsets), total ~35.7 MB ----------------
static const size_t OFF_SUM  = 0;                      // [256][256]
static const size_t OFF_FLAG = 65536;                  // int flag
static const size_t OFF_WP   = 65600;                  // 3 x [128][256] float4
static const size_t OFF_CEH  = 458816;                 // [NT][256][256]
static const size_t OFF_CEO  = 2555968;                // [NT][256][256]
static const size_t OFF_H    = 4653120;                // [NT+1][256][256]
static const size_t OFF_A2   = 6815808;                // [NT][256][256]

// x-dtype detector: if x is int64, all sampled high 32-bit words are zero.
__global__ void detect_x(const int* __restrict__ x, float* __restrict__ ws) {
    __shared__ int nonzero;
    if (threadIdx.x == 0) nonzero = 0;
    __syncthreads();
    if (x[2 * threadIdx.x + 1] != 0) nonzero = 1;   // benign same-value race
    __syncthreads();
    if (threadIdx.x == 0) *(int*)(ws + OFF_FLAG) = (nonzero == 0) ? 1 : 0;
}

// Pack weights as float4 per (k-quad, column): Wp[z][q][j] = {W_z[j][4q+c]}.
__global__ void prep_pack(const float* __restrict__ Wi2h,
                          const float* __restrict__ Wi2o,
                          const float* __restrict__ Wo2o,
                          float* __restrict__ ws) {
    const int q = blockIdx.x;            // 0..127 (k quad)
    const int z = blockIdx.y;            // 0..2
    const int j = threadIdx.x;           // 0..255 (column)
    const float* src = (z == 0) ? Wi2h : (z == 1) ? Wi2o : Wo2o;
    const float4 v = *reinterpret_cast<const float4*>(src + (size_t)j * 512 + 4 * q);
    reinterpret_cast<float4*>(ws + OFF_WP)[((size_t)z * 128 + q) * 256 + j] = v;
}

// exact-bit wave broadcast: value of v at lane l
__device__ __forceinline__ float RLf(float v, int l) {
    return __int_as_float(__builtin_amdgcn_readlane(__float_as_int(v), l));
}

// ---- kernB: e-part chains (k=0..255) for hn and o. Block = 2 subgroups x
// 128 threads; subgroup sg handles t = ti*16+sg*8 .. +7; thread covers
// columns lj and lj+128 (C=2). e broadcast via SAME-ADDRESS ds_read_b128
// (4 scalars / ~8 DS-cyc, feeds 8 FMAs x 2 cols) -> no readlanes.
// ti==0 blocks also fold the PREVIOUS phase's a2 into SUM (t-ascending).
__global__ __launch_bounds__(256) void kernB(
    const int* __restrict__ x, const float* __restrict__ emb,
    const float* __restrict__ boo, float* __restrict__ ws, int phase) {
    const int tid = threadIdx.x;
    const int sg = tid >> 7;            // subgroup 0/1
    const int lj = tid & 127;
    const int j0 = lj, j1 = lj + 128;
    const int ti = blockIdx.x;          // 0/1 (16-t tile)
    const int row = blockIdx.y;
    const int mode64 = *(const int*)(ws + OFF_FLAG);
    const float4* __restrict__ Wh4  = reinterpret_cast<const float4*>(ws + OFF_WP);
    const float4* __restrict__ Wio4 = Wh4 + (size_t)128 * 256;

    // fold previous phase's a2 into SUM (t-ascending, exact f32 chain)
    if (ti == 0 && phase > 0) {
        const size_t rb = (size_t)row * 256 + tid;
        float av[NT];
        #pragma unroll
        for (int i = 0; i < NT; ++i)
            av[i] = ws[OFF_A2 + (size_t)i * 65536 + rb];
        float s = (phase == 1) ? 0.f : ws[OFF_SUM + rb];
        const float boo_j = boo[tid];
        #pragma unroll
        for (int i = 0; i < NT; ++i) s += (av[i] + boo_j);
        ws[OFF_SUM + rb] = s;
    }

    __shared__ int toks[BT];
    __shared__ __align__(16) float eW[BT][256];
    if (tid < BT) {
        const int t = phase * NT + ti * BT + tid;
        toks[tid] = mode64 ? x[2 * (t * BSZ + row)] : x[t * BSZ + row];
    }
    __syncthreads();
    #pragma unroll
    for (int v = 0; v < BT; ++v)
        eW[v][tid] = emb[(size_t)toks[v] * HD + tid];
    __syncthreads();

    float aH[TBB][2], aO[TBB][2];
    #pragma unroll
    for (int u = 0; u < TBB; ++u) {
        aH[u][0] = 0.f; aH[u][1] = 0.f; aO[u][0] = 0.f; aO[u][1] = 0.f;
    }
    #pragma unroll 2
    for (int q = 0; q < 64; ++q) {
        const float4 whA = Wh4[(size_t)q * 256 + j0];
        const float4 whB = Wh4[(size_t)q * 256 + j1];
        const float4 woA = Wio4[(size_t)q * 256 + j0];
        const float4 woB = Wio4[(size_t)q * 256 + j1];
        #pragma unroll
        for (int u = 0; u < TBB; ++u) {
            const float4 e = *reinterpret_cast<const float4*>(&eW[sg * TBB + u][4 * q]);
            aH[u][0] = fmaf(e.x, whA.x, aH[u][0]); aH[u][1] = fmaf(e.x, whB.x, aH[u][1]);
            aO[u][0] = fmaf(e.x, woA.x, aO[u][0]); aO[u][1] = fmaf(e.x, woB.x, aO[u][1]);
            aH[u][0] = fmaf(e.y, whA.y, aH[u][0]); aH[u][1] = fmaf(e.y, whB.y, aH[u][1]);
            aO[u][0] = fmaf(e.y, woA.y, aO[u][0]); aO[u][1] = fmaf(e.y, woB.y, aO[u][1]);
            aH[u][0] = fmaf(e.z, whA.z, aH[u][0]); aH[u][1] = fmaf(e.z, whB.z, aH[u][1]);
            aO[u][0] = fmaf(e.z, woA.z, aO[u][0]); aO[u][1] = fmaf(e.z, woB.z, aO[u][1]);
            aH[u][0] = fmaf(e.w, whA.w, aH[u][0]); aH[u][1] = fmaf(e.w, whB.w, aH[u][1]);
            aO[u][0] = fmaf(e.w, woA.w, aO[u][0]); aO[u][1] = fmaf(e.w, woB.w, aO[u][1]);
        }
    }
    const size_t rb = (size_t)row * 256;
    #pragma unroll
    for (int u = 0; u < TBB; ++u) {
        const size_t off = (size_t)(ti * BT + sg * TBB + u) * 65536 + rb;
        ws[OFF_CEH + off + j0] = aH[u][0];
        ws[OFF_CEH + off + j1] = aH[u][1];
        ws[OFF_CEO + off + j0] = aO[u][0];
        ws[OFF_CEO + off + j1] = aO[u][1];
    }
}

// ---- kernC: NT sequential recurrence steps; whr[64] register-resident.
// h broadcast split across pipes: even k-quads via same-address ds_read_b128
// (DS pipe), odd k-quads via readlane (VALU) -> ~halves per-step issue wall.
__global__ __launch_bounds__(256) void kernC(
    const float* __restrict__ bih, float* __restrict__ ws, int phase) {
    const int j = threadIdx.x;
    const int lane = j & 63;
    const int row = blockIdx.x;
    const float4* __restrict__ Wh4 = reinterpret_cast<const float4*>(ws + OFF_WP);

    float4 whr[64];
    #pragma unroll
    for (int q = 0; q < 64; ++q) whr[q] = Wh4[(size_t)(64 + q) * 256 + j];

    __shared__ __align__(16) float hCur[256];
    float* __restrict__ Hp = ws + OFF_H;
    const float* __restrict__ CE = ws + OFF_CEH;
    const size_t rb = (size_t)row * 256 + j;

    const float hc = (phase == 0) ? 0.f : Hp[(size_t)NT * 65536 + rb]; // carry
    Hp[rb] = hc;                       // H[0] = h at phase start
    hCur[j] = hc;
    const float bih_j = bih[j];
    float ceCur = CE[rb];
    __syncthreads();

    #pragma unroll 1
    for (int i = 0; i < NT; ++i) {
        const float ceNext = (i + 1 < NT) ? CE[(size_t)(i + 1) * 65536 + rb] : 0.f;
        const float4 h4 = *reinterpret_cast<const float4*>(&hCur[4 * lane]);
        float ah = ceCur;
        #pragma unroll
        for (int p2 = 0; p2 < 32; ++p2) {
            const int q0 = 2 * p2, q1 = 2 * p2 + 1;
            const float4 a = *reinterpret_cast<const float4*>(&hCur[4 * q0]); // DS bcast
            ah = fmaf(a.x, whr[q0].x, ah);
            ah = fmaf(a.y, whr[q0].y, ah);
            ah = fmaf(a.z, whr[q0].z, ah);
            ah = fmaf(a.w, whr[q0].w, ah);
            ah = fmaf(RLf(h4.x, q1), whr[q1].x, ah);
            ah = fmaf(RLf(h4.y, q1), whr[q1].y, ah);
            ah = fmaf(RLf(h4.z, q1), whr[q1].z, ah);
            ah = fmaf(RLf(h4.w, q1), whr[q1].w, ah);
        }
        const float hn = ah + bih_j;                   // + b_i2h
        Hp[(size_t)(i + 1) * 65536 + rb] = hn;         // publish to ws
        __syncthreads();                               // all reads done
        hCur[j] = hn;
        ceCur = ceNext;
        __syncthreads();                               // hCur published
    }
}

// ---- kernD: finish o (h-part) and out-chains. Block = 2 subgroups x 128
// threads (C=2 cols: lj, lj+128); subgroup sg handles t = ti*16+sg*8..+7.
// h/o broadcast via SAME-ADDRESS ds_read_b128 from LDS-staged hS/oS.
// Chains 1 (o h-part, h_t) and 2 (out hn-part, h_{t+1}) fused per q via the
// 9-quad hq window; chain 3 (out o-part) after the oS hop.
__global__ __launch_bounds__(256) void kernD(
    const float* __restrict__ bio, float* __restrict__ ws, int phase) {
    const int tid = threadIdx.x;
    const int sg = tid >> 7;
    const int lj = tid & 127;
    const int j0 = lj, j1 = lj + 128;
    const int ti = blockIdx.x;          // 0/1
    const int row = blockIdx.y;
    const float4* __restrict__ Wh4  = reinterpret_cast<const float4*>(ws + OFF_WP);
    const float4* __restrict__ Wio4 = Wh4 + (size_t)128 * 256;
    const float4* __restrict__ Woo4 = Wh4 + (size_t)256 * 256;

    __shared__ __align__(16) float hS[BT + 1][256];   // 17 KB
    __shared__ __align__(16) float oS[BT][256];       // 16 KB
    const float* __restrict__ Hp = ws + OFF_H;
    const size_t rb = (size_t)row * 256;

    #pragma unroll
    for (int v = 0; v <= BT; ++v)
        hS[v][tid] = Hp[(size_t)(ti * BT + v) * 65536 + rb + tid];
    float co[TBB][2], a2[TBB][2];
    #pragma unroll
    for (int u = 0; u < TBB; ++u) {
        const size_t off = OFF_CEO + (size_t)(ti * BT + sg * TBB + u) * 65536 + rb;
        co[u][0] = ws[off + j0];
        co[u][1] = ws[off + j1];
        a2[u][0] = 0.f; a2[u][1] = 0.f;
    }
    __syncthreads();

    // fused chains 1+2: per q read 9 h-quads (same-address broadcasts)
    #pragma unroll 2
    for (int q = 0; q < 64; ++q) {
        const float4 w1A = Wio4[(size_t)(64 + q) * 256 + j0];
        const float4 w1B = Wio4[(size_t)(64 + q) * 256 + j1];
        const float4 w2A = Woo4[(size_t)q * 256 + j0];
        const float4 w2B = Woo4[(size_t)q * 256 + j1];
        float4 hq[TBB + 1];
        #pragma unroll
        for (int v = 0; v <= TBB; ++v)
            hq[v] = *reinterpret_cast<const float4*>(&hS[sg * TBB + v][4 * q]);
        #pragma unroll
        for (int u = 0; u < TBB; ++u) {
            co[u][0] = fmaf(hq[u].x, w1A.x, co[u][0]);
            co[u][1] = fmaf(hq[u].x, w1B.x, co[u][1]);
            co[u][0] = fmaf(hq[u].y, w1A.y, co[u][0]);
            co[u][1] = fmaf(hq[u].y, w1B.y, co[u][1]);
            co[u][0] = fmaf(hq[u].z, w1A.z, co[u][0]);
            co[u][1] = fmaf(hq[u].z, w1B.z, co[u][1]);
            co[u][0] = fmaf(hq[u].w, w1A.w, co[u][0]);
            co[u][1] = fmaf(hq[u].w, w1B.w, co[u][1]);
            a2[u][0] = fmaf(hq[u + 1].x, w2A.x, a2[u][0]);
            a2[u][1] = fmaf(hq[u + 1].x, w2B.x, a2[u][1]);
            a2[u][0] = fmaf(hq[u + 1].y, w2A.y, a2[u][0]);
            a2[u][1] = fmaf(hq[u + 1].y, w2B.y, a2[u][1]);
            a2[u][0] = fmaf(hq[u + 1].z, w2A.z, a2[u][0]);
            a2[u][1] = fmaf(hq[u + 1].z, w2B.z, a2[u][1]);
            a2[u][0] = fmaf(hq[u + 1].w, w2A.w, a2[u][0]);
            a2[u][1] = fmaf(hq[u + 1].w, w2B.w, a2[u][1]);
        }
    }
    const float bio_j0 = bio[j0], bio_j1 = bio[j1];
    #pragma unroll
    for (int u = 0; u < TBB; ++u) {
        oS[sg * TBB + u][j0] = co[u][0] + bio_j0;     // + b_i2o
        oS[sg * TBB + u][j1] = co[u][1] + bio_j1;
    }
    __syncthreads();

    // chain 3: out o-part (k = 256..511)
    #pragma unroll 2
    for (int q = 0; q < 64; ++q) {
        const float4 w3A = Woo4[(size_t)(64 + q) * 256 + j0];
        const float4 w3B = Woo4[(size_t)(64 + q) * 256 + j1];
        #pragma unroll
        for (int u = 0; u < TBB; ++u) {
            const float4 o4 = *reinterpret_cast<const float4*>(&oS[sg * TBB + u][4 * q]);
            a2[u][0] = fmaf(o4.x, w3A.x, a2[u][0]);
            a2[u][1] = fmaf(o4.x, w3B.x, a2[u][1]);
            a2[u][0] = fmaf(o4.y, w3A.y, a2[u][0]);
            a2[u][1] = fmaf(o4.y, w3B.y, a2[u][1]);
            a2[u][0] = fmaf(o4.z, w3A.z, a2[u][0]);
            a2[u][1] = fmaf(o4.z, w3B.z, a2[u][1]);
            a2[u][0] = fmaf(o4.w, w3A.w, a2[u][0]);
            a2[u][1] = fmaf(o4.w, w3B.w, a2[u][1]);
        }
    }
    #pragma unroll
    for (int u = 0; u < TBB; ++u) {
        const size_t off = OFF_A2 + (size_t)(ti * BT + sg * TBB + u) * 65536 + rb;
        ws[off + j0] = a2[u][0];
        ws[off + j1] = a2[u][1];
    }
}

// encoded: fold LAST phase's a2 (t-ascending, exact), /1024; logits; softmax;
// first-index argmax over f32 lp.
__global__ __launch_bounds__(64) void final_k(
    const float* __restrict__ Wpred, const float* __restrict__ bpred,
    const float* __restrict__ boo, const float* __restrict__ ws,
    float* __restrict__ out) {
    const int b = blockIdx.x, o = threadIdx.x;
    __shared__ float enc[256];
    __shared__ float exs[64];
    __shared__ float s32s;

    #pragma unroll
    for (int u = 0; u < 4; ++u) {
        const int j = o * 4 + u;
        const size_t rb = (size_t)b * 256 + j;
        float av[NT];
        #pragma unroll
        for (int i = 0; i < NT; ++i)
            av[i] = ws[OFF_A2 + (size_t)i * 65536 + rb];
        float s = ws[OFF_SUM + rb];
        const float boo_j = boo[j];
        #pragma unroll
        for (int i = 0; i < NT; ++i) s += (av[i] + boo_j);
        enc[j] = s * (1.0f / 1024.0f);
    }
    __syncthreads();

    float acc = 0.f;
    for (int e = 0; e < 256; ++e)
        acc = fmaf(enc[e], Wpred[(size_t)o * 256 + e], acc);
    acc += bpred[o];                      // logits[b][o], f32

    float m = acc;
    #pragma unroll
    for (int d = 1; d < 64; d <<= 1) m = fmaxf(m, __shfl_xor(m, d));
    const float sh = acc - m;
    const float ex = (float)exp((double)sh);
    exs[o] = ex;
    __syncthreads();
    if (o == 0) {
        double sd = 0.0;
        for (int i = 0; i < 64; ++i) sd += (double)exs[i];
        s32s = (float)sd;
    }
    __syncthreads();
    const float log_s = (float)log((double)s32s);
    const float lp = sh - log_s;
    const float pr = (float)exp((double)lp);

    float av = lp; int ai = o;
    #pragma unroll
    for (int d = 1; d < 64; d <<= 1) {
        const float ov = __shfl_xor(av, d);
        const int oi = __shfl_xor(ai, d);
        if (ov > av || (ov == av && oi < ai)) { av = ov; ai = oi; }
    }

    out[BSZ + (size_t)b * OUTC + o] = lp;              // logprobs
    out[BSZ + 16384 + (size_t)b * OUTC + o] = pr;      // probs
    if (o == 0) out[b] = (float)ai;                    // preds
}

// ---------------- host ----------------
extern "C" void kernel_launch(void* const* d_in, const int* in_sizes, int n_in,
                              void* d_out, int out_size, void* d_ws, size_t ws_size,
                              hipStream_t stream) {
    const int*   x     = (const int*)d_in[0];
    const float* emb   = (const float*)d_in[1];
    const float* Wi2h  = (const float*)d_in[2];
    const float* b_ih  = (const float*)d_in[3];
    const float* Wi2o  = (const float*)d_in[4];
    const float* b_io  = (const float*)d_in[5];
    const float* Wo2o  = (const float*)d_in[6];
    const float* b_oo  = (const float*)d_in[7];
    const float* Wpred = (const float*)d_in[8];
    const float* b_p   = (const float*)d_in[9];
    float* ws  = (float*)d_ws;
    float* out = (float*)d_out;

    detect_x<<<1, 256, 0, stream>>>(x, ws);
    prep_pack<<<dim3(128, 3), 256, 0, stream>>>(Wi2h, Wi2o, Wo2o, ws);

    for (int p = 0; p < NPHASE; ++p) {
        kernB<<<dim3(2, 256), 256, 0, stream>>>(x, emb, b_oo, ws, p);
        kernC<<<dim3(256), 256, 0, stream>>>(b_ih, ws, p);
        kernD<<<dim3(2, 256), 256, 0, stream>>>(b_io, ws, p);
    }
    final_k<<<dim3(256), 64, 0, stream>>>(Wpred, b_p, b_oo, ws, out);
}